// Round 4
// baseline (195.070 us; speedup 1.0000x reference)
//
#include <hip/hip_runtime.h>

#define HH 256
#define WW 256
#define CHN 256
#define PAD 4
#define HW (HH * WW)

#define TW 32      // tile width (pixels)
#define TH 16      // tile height (pixels)
#define PR 24      // patch rows = TH + 8
#define PC 40      // patch cols = TW + 8
#define PCP 41     // padded LDS col stride (bank-conflict fix)
#define NSPLIT 4   // channel splits across blocks
#define CPB 64     // channels per block
#define NG 16      // channel groups of 4 per block

__device__ __forceinline__ void fma4(float4& a, const float4& k, float w) {
    a.x = fmaf(k.x, w, a.x);
    a.y = fmaf(k.y, w, a.y);
    a.z = fmaf(k.z, w, a.z);
    a.w = fmaf(k.w, w, a.w);
}

__global__ __launch_bounds__(256, 2)
void prop_kernel(const float* __restrict__ key, const float* __restrict__ wts,
                 float* __restrict__ out) {
    // double-buffered key patch: [buf][row][col][4ch] as float4
    __shared__ float4 smem[2][PR][PCP];

    const int tid = threadIdx.x;
    const int tw  = tid & 15;   // w-pair index 0..15
    const int th  = tid >> 4;   // h index 0..15
    const int w0  = blockIdx.x * TW;
    const int h0  = blockIdx.y * TH;
    const int c0  = blockIdx.z * CPB;
    const int h   = h0 + th;
    const int w   = w0 + 2 * tw;

    // ---- preload per-pixel weights for the 2 owned pixels (registers) ----
    float wt0[81], wt1[81];
    {
        const float* wp = wts + h * WW + w;   // w even -> 8B aligned
        #pragma unroll
        for (int t = 0; t < 81; ++t) {
            float2 v = *reinterpret_cast<const float2*>(wp + t * HW);
            wt0[t] = v.x;
            wt1[t] = v.y;
        }
    }

    // ---- stage channel-group 0 into buffer 0 ----
    {
        const float* kp = key + (size_t)c0 * HW;
        for (int p = tid; p < PR * PC; p += 256) {
            int row = p / PC;
            int col = p - row * PC;
            int gh  = h0 - PAD + row;
            int gw  = w0 - PAD + col;
            float4 v = make_float4(0.f, 0.f, 0.f, 0.f);
            if ((unsigned)gh < HH && (unsigned)gw < WW) {
                const float* q = kp + gh * WW + gw;
                v.x = q[0];
                v.y = q[HW];
                v.z = q[2 * HW];
                v.w = q[3 * HW];
            }
            smem[0][row][col] = v;
        }
    }
    __syncthreads();

    for (int g = 0; g < NG; ++g) {
        // ---- prefetch next channel group into the other buffer ----
        if (g + 1 < NG) {
            const float* kp = key + (size_t)(c0 + (g + 1) * 4) * HW;
            float4* dst = &smem[(g + 1) & 1][0][0];
            for (int p = tid; p < PR * PC; p += 256) {
                int row = p / PC;
                int col = p - row * PC;
                int gh  = h0 - PAD + row;
                int gw  = w0 - PAD + col;
                float4 v = make_float4(0.f, 0.f, 0.f, 0.f);
                if ((unsigned)gh < HH && (unsigned)gw < WW) {
                    const float* q = kp + gh * WW + gw;
                    v.x = q[0];
                    v.y = q[HW];
                    v.z = q[2 * HW];
                    v.w = q[3 * HW];
                }
                dst[row * PCP + col] = v;
            }
        }

        // ---- compute 2 pixels x 4 channels from current buffer ----
        const float4* bp = &smem[g & 1][0][0] + th * PCP + 2 * tw;
        float4 a0 = make_float4(0.f, 0.f, 0.f, 0.f);
        float4 a1 = make_float4(0.f, 0.f, 0.f, 0.f);
        #pragma unroll
        for (int r = 0; r < 9; ++r) {
            #pragma unroll
            for (int c = 0; c < 10; ++c) {
                float4 k4 = bp[r * PCP + c];           // ds_read_b128, imm offset
                if (c < 9)  fma4(a0, k4, wt0[r * 9 + c]);
                if (c >= 1) fma4(a1, k4, wt1[r * 9 + c - 1]);
            }
        }

        // ---- store 2 px x 4 ch ----
        const int cb = c0 + g * 4;
        float* op = out + (size_t)cb * HW + h * WW + w;
        *reinterpret_cast<float2*>(op)          = make_float2(a0.x, a1.x);
        *reinterpret_cast<float2*>(op + HW)     = make_float2(a0.y, a1.y);
        *reinterpret_cast<float2*>(op + 2 * HW) = make_float2(a0.z, a1.z);
        *reinterpret_cast<float2*>(op + 3 * HW) = make_float2(a0.w, a1.w);

        __syncthreads();
    }
}

extern "C" void kernel_launch(void* const* d_in, const int* in_sizes, int n_in,
                              void* d_out, int out_size, void* d_ws, size_t ws_size,
                              hipStream_t stream) {
    const float* key = (const float*)d_in[0];   // (1,256,256,256) f32
    const float* wts = (const float*)d_in[1];   // (1,81,256,256)  f32
    float* out = (float*)d_out;                 // (1,256,256,256) f32

    dim3 grid(WW / TW, HH / TH, NSPLIT);        // 8 x 16 x 4 = 512 blocks
    prop_kernel<<<grid, 256, 0, stream>>>(key, wts, out);
}